// Round 2
// baseline (2050.233 us; speedup 1.0000x reference)
//
#include <hip/hip_runtime.h>

// Problem constants (from reference setup_inputs)
#define KK   27
#define MM   80000
#define NN   200000
#define INC  64
#define OUTC 128
#define RIN  48
#define ROUT 96

#define BLOCKS_PER_K 80
#define ENTRIES_PER_BLOCK ((MM + BLOCKS_PER_K - 1) / BLOCKS_PER_K)  // 1000

// 192 threads = 2 entries x 96 output channels.
// Each thread keeps its oc-column of w[k] (48 floats) in registers.
__global__ __launch_bounds__(192)
void sparse_conv_scatter(const float* __restrict__ feat,
                         const float* __restrict__ w,
                         const int* __restrict__ imap,
                         const int* __restrict__ omap,
                         float* __restrict__ out)
{
    const int k   = blockIdx.y;
    const int oc  = threadIdx.x % 96;
    const int sub = threadIdx.x / 96;

    // Load this thread's weight column w[k][0..47][oc] into registers.
    const float* wk = w + (size_t)k * INC * OUTC + oc;
    float wr[RIN];
    #pragma unroll
    for (int i = 0; i < RIN; ++i) wr[i] = wk[(size_t)i * OUTC];

    const int m0 = blockIdx.x * ENTRIES_PER_BLOCK;
    const int m1 = min(m0 + ENTRIES_PER_BLOCK, MM);

    const int* imk = imap + (size_t)k * MM;
    const int* omk = omap + (size_t)k * MM;

    for (int m = m0 + sub; m < m1; m += 2) {
        const int fin  = imk[m];
        const int fout = omk[m];
        const float4* f4 = (const float4*)(feat + (size_t)fin * RIN);

        float4 v[RIN / 4];
        #pragma unroll
        for (int j = 0; j < RIN / 4; ++j) v[j] = f4[j];

        float acc = 0.f;
        #pragma unroll
        for (int j = 0; j < RIN / 4; ++j) {
            acc += v[j].x * wr[4 * j + 0];
            acc += v[j].y * wr[4 * j + 1];
            acc += v[j].z * wr[4 * j + 2];
            acc += v[j].w * wr[4 * j + 3];
        }
        // fire-and-forget device-scope fp32 atomic
        atomicAdd(&out[(size_t)fout * ROUT + oc], acc);
    }
}

extern "C" void kernel_launch(void* const* d_in, const int* in_sizes, int n_in,
                              void* d_out, int out_size, void* d_ws, size_t ws_size,
                              hipStream_t stream)
{
    const float* features = (const float*)d_in[0];
    const float* kernel_w = (const float*)d_in[1];
    const int*   in_map   = (const int*)d_in[2];
    const int*   out_map  = (const int*)d_in[3];
    float*       out      = (float*)d_out;

    hipMemsetAsync(d_out, 0, (size_t)out_size * sizeof(float), stream);

    dim3 grid(BLOCKS_PER_K, KK);
    sparse_conv_scatter<<<grid, 192, 0, stream>>>(features, kernel_w, in_map, out_map, out);
}